// Round 10
// baseline (699.692 us; speedup 1.0000x reference)
//
#include <hip/hip_runtime.h>
#include <cstdint>
#include <cstddef>

// Problem constants (fixed by the reference setup)
#define N_NODES 50000
#define N_PAD   50048   // 391 * 128 = 782 * 64
#define N_EDGES 800000
#define F_INPUT 128
#define DIM 256
#define NLAYERS 3
#define NGRAPHS 512
#define NBH 64          // histogram/fill blocks
#define EPB 12500       // edges per histogram block
#define NGB 391         // GEMM m-blocks (N_PAD/128)
#define SLS ((size_t)N_PAD * 32)   // slice stride (elements), slice-major activations

typedef __bf16 bf16_t;
typedef bf16_t bf16x8 __attribute__((ext_vector_type(8)));
typedef float f32x4 __attribute__((ext_vector_type(4)));

__device__ __forceinline__ float bf2f(unsigned short u) {
    union { unsigned u32; float f; } x; x.u32 = ((unsigned)u) << 16; return x.f;
}
__device__ __forceinline__ unsigned short f2bf(float f) {
    union { float f; unsigned u; } x; x.f = f;
    unsigned r = (x.u + 0x7fffu + ((x.u >> 16) & 1u)) >> 16;
    return (unsigned short)r;
}

// MFMA-fragment-order packing for the B operand (weights): wave fragment load is
// 64 lanes x 16B contiguous (1KB coalesced, L2-resident — no LDS needed).
__device__ __forceinline__ size_t frag_off(int n, int k, int K) {
    int nb = n >> 7, half = (n >> 6) & 1, j = (n >> 4) & 3, lm = n & 15;
    int ks = k >> 5, q = (k >> 3) & 3, e = k & 7;
    return ((size_t)(((nb * 2 + half) * 4 + j) * (K >> 5) + ks)) * 512 + (q * 16 + lm) * 8 + e;
}

// ---- merged prep: weight hi/lo split into fragment order AND x f32->bf16 (6250 blocks)
__global__ void k_prep(const float* __restrict__ W_enc, const float* __restrict__ W1,
                       const float* __restrict__ W2, const float* __restrict__ x,
                       unsigned short* __restrict__ wench, unsigned short* __restrict__ wencl,
                       unsigned short* __restrict__ w1h, unsigned short* __restrict__ w1l,
                       unsigned short* __restrict__ w2h, unsigned short* __restrict__ w2l,
                       unsigned short* __restrict__ xb) {
    int idx = blockIdx.x * 256 + threadIdx.x;
    if (idx < 32768) {                       // W_enc [128][256], K=128
        float w = W_enc[idx];
        int k = idx >> 8, n = idx & 255;
        unsigned short h = f2bf(w), lo = f2bf(w - bf2f(h));
        size_t o = frag_off(n, k, 128);
        wench[o] = h; wencl[o] = lo;
    } else if (idx < 32768 + 196608) {       // W1 [3][256][256], K=256
        int j = idx - 32768;
        int l = j >> 16, r = j & 65535, k = r >> 8, n = r & 255;
        float w = W1[j];
        unsigned short h = f2bf(w), lo = f2bf(w - bf2f(h));
        size_t o = (size_t)l * 65536 + frag_off(n, k, 256);
        w1h[o] = h; w1l[o] = lo;
    } else if (idx < 32768 + 2 * 196608) {   // W2
        int j = idx - 32768 - 196608;
        int l = j >> 16, r = j & 65535, k = r >> 8, n = r & 255;
        float w = W2[j];
        unsigned short h = f2bf(w), lo = f2bf(w - bf2f(h));
        size_t o = (size_t)l * 65536 + frag_off(n, k, 256);
        w2h[o] = h; w2l[o] = lo;
    }
    if (idx < (N_NODES * F_INPUT) / 4) {     // x -> bf16, 4 at a time
        float4 v = reinterpret_cast<const float4*>(x)[idx];
        ushort4 o;
        o.x = f2bf(v.x); o.y = f2bf(v.y); o.z = f2bf(v.z); o.w = f2bf(v.w);
        reinterpret_cast<ushort4*>(xb)[idx] = o;
    }
}

// ---- per-block LDS histogram of dst (packed 2x16-bit, 2 node-range passes)
__global__ __launch_bounds__(512) void k_count(const int* __restrict__ dst,
                                               unsigned* __restrict__ slab) {
    __shared__ unsigned bins[16384];
    int b = blockIdx.x, t = threadIdx.x;
    int e0 = b * EPB, e1 = e0 + EPB;
    for (int pass = 0; pass < 2; ++pass) {
        int lo = pass << 15;
        int words = pass ? 8616 : 16384;
        for (int w = t; w < 16384; w += 512) bins[w] = 0;
        __syncthreads();
        for (int e = e0 + t; e < e1; e += 512) {
            int r = dst[e] - lo;
            if ((unsigned)r < 32768u)
                atomicAdd(&bins[r >> 1], 1u << ((r & 1) * 16));
        }
        __syncthreads();
        unsigned* out = slab + b * 25000 + (pass ? 16384 : 0);
        for (int w = t; w < words; w += 512) out[w] = bins[w];
        __syncthreads();
    }
}

// ---- reduce count slabs -> deg; graph boundaries from sorted batch -> gstart
__global__ void k_degred(const unsigned* __restrict__ slab, const int* __restrict__ batch,
                         int* __restrict__ deg, int* __restrict__ gstart) {
    int i = blockIdx.x * 256 + threadIdx.x;
    if (i < 25000) {
        unsigned s = 0;
#pragma unroll 8
        for (int b = 0; b < NBH; ++b) s += slab[b * 25000 + i];
        deg[2 * i] = s & 0xffff;
        deg[2 * i + 1] = s >> 16;
    }
    if (i < N_NODES) {
        int bt = batch[i];
        int pb = (i == 0) ? -1 : batch[i - 1];
        if (bt != pb)
            for (int g = pb + 1; g <= bt; ++g) gstart[g] = i;
        if (i == N_NODES - 1)
            for (int g = bt + 1; g <= NGRAPHS; ++g) gstart[g] = N_NODES;
    }
}

// ---- degree-bucket histogram (64 buckets, LDS-privatized)
__global__ void k_dhist(const int* __restrict__ deg, int* __restrict__ dcnt) {
    __shared__ int h[64];
    int t = threadIdx.x, i = blockIdx.x * 256 + t;
    if (t < 64) h[t] = 0;
    __syncthreads();
    if (i < N_NODES) atomicAdd(&h[min(deg[i], 63)], 1);
    __syncthreads();
    if (t < 64 && h[t]) atomicAdd(&dcnt[t], h[t]);
}

// ---- exclusive scan of 64 bucket counts -> global cursors
__global__ void k_dscan(const int* __restrict__ dcnt, int* __restrict__ dcur) {
    __shared__ int s[64];
    int t = threadIdx.x;
    int v = dcnt[t];
    s[t] = v; __syncthreads();
    for (int off = 1; off < 64; off <<= 1) {
        int x = (t >= off) ? s[t - off] : 0;
        __syncthreads(); s[t] += x; __syncthreads();
    }
    dcur[t] = s[t] - v;
}

// ---- scatter nodes into degree-sorted perm (block reserves bucket ranges)
__global__ void k_dfill(const int* __restrict__ deg, int* __restrict__ dcur,
                        int* __restrict__ perm) {
    __shared__ int h[64], base[64], cur[64];
    int t = threadIdx.x, i = blockIdx.x * 256 + t;
    if (t < 64) h[t] = 0;
    __syncthreads();
    int b = -1;
    if (i < N_NODES) { b = min(deg[i], 63); atomicAdd(&h[b], 1); }
    __syncthreads();
    if (t < 64) {
        base[t] = h[t] ? atomicAdd(&dcur[t], h[t]) : 0;
        cur[t] = 0;
    }
    __syncthreads();
    if (b >= 0) {
        int pos = atomicAdd(&cur[b], 1);
        perm[base[b] + pos] = i;
    }
}

// ---- scan step 1: per-block inclusive scan of deg (no padding)
__global__ void k_scan1(const int* __restrict__ deg, int* __restrict__ rp1,
                        int* __restrict__ bsum) {
    __shared__ int s[256];
    int t = threadIdx.x, b = blockIdx.x, i = b * 256 + t;
    int v = (i < N_NODES) ? deg[i] : 0;
    s[t] = v; __syncthreads();
    for (int off = 1; off < 256; off <<= 1) {
        int x = (t >= off) ? s[t - off] : 0;
        __syncthreads(); s[t] += x; __syncthreads();
    }
    if (i < N_NODES) rp1[i] = s[t];
    if (t == 255) bsum[b] = s[255];
}

// ---- scan step 2: exclusive scan of block sums
__global__ void k_scan2(const int* __restrict__ bsum, int* __restrict__ boff, int nb) {
    __shared__ int s[256];
    int t = threadIdx.x;
    int v = (t < nb) ? bsum[t] : 0;
    s[t] = v; __syncthreads();
    for (int off = 1; off < 256; off <<= 1) {
        int x = (t >= off) ? s[t - off] : 0;
        __syncthreads(); s[t] += x; __syncthreads();
    }
    if (t < nb) boff[t] = s[t] - v;
}

// ---- scan step 3: add block offsets; finalize row_ptr[0]
__global__ void k_scan3(int* __restrict__ row_ptr, const int* __restrict__ boff) {
    int t = threadIdx.x, b = blockIdx.x, i = b * 256 + t;
    if (i < N_NODES) row_ptr[1 + i] += boff[b];
    if (i == 0) row_ptr[0] = 0;
}

// ---- per-(block,node) exclusive bases from count slabs
__global__ void k_base(const unsigned* __restrict__ slab, const int* __restrict__ row_ptr,
                       int* __restrict__ base) {
    int n = blockIdx.x * 256 + threadIdx.x;
    if (n >= N_NODES) return;
    int w = n >> 1, sh = (n & 1) * 16;
    int cur = row_ptr[n];
#pragma unroll 4
    for (int b = 0; b < NBH; ++b) {
        base[b * N_NODES + n] = cur;
        cur += (slab[b * 25000 + w] >> sh) & 0xffff;
    }
}

// ---- CSR fill with LDS cursors (no global atomics), u16 indices
__global__ __launch_bounds__(512) void k_fill2(const int* __restrict__ src,
                                               const int* __restrict__ dst,
                                               const int* __restrict__ base,
                                               unsigned short* __restrict__ csr16) {
    __shared__ unsigned bins[16384];
    int b = blockIdx.x, t = threadIdx.x;
    int e0 = b * EPB, e1 = e0 + EPB;
    for (int pass = 0; pass < 2; ++pass) {
        int lo = pass << 15;
        for (int w = t; w < 16384; w += 512) bins[w] = 0;
        __syncthreads();
        for (int e = e0 + t; e < e1; e += 512) {
            int d = dst[e];
            int r = d - lo;
            if ((unsigned)r < 32768u) {
                int sh = (r & 1) * 16;
                unsigned old = atomicAdd(&bins[r >> 1], 1u << sh);
                int local = (old >> sh) & 0xffff;
                csr16[base[b * N_NODES + d] + local] = (unsigned short)src[e];
            }
        }
        __syncthreads();
    }
}

// ---- XCD-sliced, degree-sorted plain-sum aggregation.
// slice = blockIdx.x & 7 (slice table 3.2MB + u16 index ~1.6MB ≈ L2-resident/XCD).
// One wave = 16 perm-consecutive nodes (near-equal degree -> minimal divergence)
// x one slice; lane group of 4 owns a node's 64B slice row (16B/lane).
__global__ void k_agg(const unsigned short* __restrict__ zin, const int* __restrict__ row_ptr,
                      const unsigned short* __restrict__ csr16, const int* __restrict__ perm,
                      unsigned short* __restrict__ z0) {
    int sl = blockIdx.x & 7;
    int wid = threadIdx.x >> 6, lane = threadIdx.x & 63;
    int g = lane >> 2, c = lane & 3;                    // node-group, 16B chunk
    int gi = (blockIdx.x >> 3) * 64 + wid * 16 + g;     // grid.x = 782*8
    bool valid = gi < N_NODES;
    int node = valid ? perm[gi] : 0;
    const unsigned short* table = zin + (size_t)sl * SLS;
    int e = 0, end = 0;
    if (valid) { e = row_ptr[node]; end = row_ptr[node + 1]; }
    float acc[8] = {0.f, 0.f, 0.f, 0.f, 0.f, 0.f, 0.f, 0.f};
    int srcn = (e < end) ? (int)csr16[e] : 0;
    while (e < end) {
        int cur = srcn;
        ++e;
        if (e < end) srcn = (int)csr16[e];
        uint4 v = *(const uint4*)(table + (size_t)cur * 32 + c * 8);
        const unsigned short* pv = (const unsigned short*)&v;
#pragma unroll
        for (int i = 0; i < 8; ++i) acc[i] += bf2f(pv[i]);
    }
    if (valid) {
        uint4 ov = *(const uint4*)(table + (size_t)node * 32 + c * 8);
        const unsigned short* po = (const unsigned short*)&ov;
        uint4 o;
        unsigned short* pw = (unsigned short*)&o;
#pragma unroll
        for (int i = 0; i < 8; ++i) pw[i] = f2bf(bf2f(po[i]) + acc[i]);
        *(uint4*)(z0 + (size_t)sl * SLS + (size_t)node * 32 + c * 8) = o;
    }
}

// ---- MFMA GEMM, LDS-free: A fragments loaded directly global->VGPR per wave
// (2-deep register pipeline, zero barriers in the K-loop); B direct-from-L2
// pre-packed coalesced fragments. AS/CS: A / C slice-major [8][N_PAD][32].
template <int K, bool AS, bool CS, bool RELU, bool STATS>
__global__ __launch_bounds__(256) void k_gemm(const unsigned short* __restrict__ A,
                                              const unsigned short* __restrict__ Whi,
                                              const unsigned short* __restrict__ Wlo,
                                              const float* __restrict__ bias,
                                              unsigned short* __restrict__ C,
                                              float* __restrict__ statsbuf, int M) {
    constexpr int KS = K / 32;
    __shared__ float st[2][2][128];
    const int tid = threadIdx.x;
    const int m0 = blockIdx.x * 128;
    const int nb = blockIdx.y;
    const int wid = tid >> 6, lane = tid & 63;
    const int wm = (wid & 1) * 64, wn = (wid >> 1) * 64;
    const int lm = lane & 15, q = lane >> 4;

    const unsigned short* fh = Whi + (size_t)((nb * 2 + (wid >> 1)) * 4) * KS * 512 + lane * 8;
    const unsigned short* fl = Wlo + (size_t)((nb * 2 + (wid >> 1)) * 4) * KS * 512 + lane * 8;

    const unsigned short* ap[4];
#pragma unroll
    for (int i = 0; i < 4; ++i) {
        int row = m0 + wm + i * 16 + lm;
        ap[i] = AS ? A + (size_t)row * 32 + q * 8
                   : A + (size_t)row * K + q * 8;
    }

    f32x4 acc[4][4];
#pragma unroll
    for (int i = 0; i < 4; ++i)
#pragma unroll
        for (int j = 0; j < 4; ++j) acc[i][j] = (f32x4){0.f, 0.f, 0.f, 0.f};

    bf16x8 af[2][4], bh[2][4], bl[2][4];
#pragma unroll
    for (int i = 0; i < 4; ++i)
        af[0][i] = *reinterpret_cast<const bf16x8*>(ap[i]);
#pragma unroll
    for (int j = 0; j < 4; ++j) {
        bh[0][j] = *reinterpret_cast<const bf16x8*>(fh + (size_t)j * KS * 512);
        bl[0][j] = *reinterpret_cast<const bf16x8*>(fl + (size_t)j * KS * 512);
    }
#pragma unroll
    for (int ks = 0; ks < KS; ++ks) {
        const int cur = ks & 1, nxt = cur ^ 1;
        if (ks + 1 < KS) {
            size_t astep = AS ? (size_t)(ks + 1) * SLS : (size_t)(ks + 1) * 32;
#pragma unroll
            for (int i = 0; i < 4; ++i)
                af[nxt][i] = *reinterpret_cast<const bf16x8*>(ap[i] + astep);
#pragma unroll
            for (int j = 0; j < 4; ++j) {
                bh[nxt][j] = *reinterpret_cast<const bf16x8*>(fh + (size_t)(j * KS + ks + 1) * 512);
                bl[nxt][j] = *reinterpret_cast<const bf16x8*>(fl + (size_t)(j * KS + ks + 1) * 512);
            }
        }
#pragma unroll
        for (int i = 0; i < 4; ++i)
#pragma unroll
            for (int j = 0; j < 4; ++j) {
                acc[i][j] = __builtin_amdgcn_mfma_f32_16x16x32_bf16(af[cur][i], bl[cur][j], acc[i][j], 0, 0, 0);
                acc[i][j] = __builtin_amdgcn_mfma_f32_16x16x32_bf16(af[cur][i], bh[cur][j], acc[i][j], 0, 0, 0);
            }
    }
    float bv[4];
#pragma unroll
    for (int j = 0; j < 4; ++j) bv[j] = bias[nb * 128 + wn + j * 16 + lm];
#pragma unroll
    for (int j = 0; j < 4; ++j) {
        int col = nb * 128 + wn + j * 16 + lm;
        unsigned short* cp = CS ? C + (size_t)(col >> 5) * SLS + (col & 31)
                                : C + col;
        float s = 0.f, s2 = 0.f;
#pragma unroll
        for (int i = 0; i < 4; ++i) {
            int row0 = m0 + wm + i * 16 + q * 4;
#pragma unroll
            for (int r = 0; r < 4; ++r) {
                int row = row0 + r;
                if (row < M) {
                    float v = acc[i][j][r] + bv[j];
                    if (STATS) { s += v; s2 = fmaf(v, v, s2); }
                    if (RELU) v = fmaxf(v, 0.f);
                    cp[(size_t)row * (CS ? 32 : DIM)] = f2bf(v);
                }
            }
        }
        if (STATS) {
            s += __shfl_xor(s, 16); s += __shfl_xor(s, 32);
            s2 += __shfl_xor(s2, 16); s2 += __shfl_xor(s2, 32);
            if (q == 0) {
                st[0][wid & 1][wn + j * 16 + lm] = s;
                st[1][wid & 1][wn + j * 16 + lm] = s2;
            }
        }
    }
    if (STATS) {
        __syncthreads();
        if (tid < 256) {
            int sel = tid >> 7, cl2 = tid & 127;
            float v = st[sel][0][cl2] + st[sel][1][cl2];
            statsbuf[(size_t)(blockIdx.y * gridDim.x + blockIdx.x) * 256 + sel * 128 + cl2] = v;
        }
    }
}

// ---- stats reduce stage 1: 32 blocks x 512 thr, partial sums over slab chunks
__global__ __launch_bounds__(512) void k_statred1(const float* __restrict__ statsbuf,
                                                  float* __restrict__ spart) {
    int b = blockIdx.x, t = threadIdx.x;
    int is2 = t >> 8, c = t & 255;
    int by = c >> 7, cl = c & 127;
    int x0 = b * 13, x1 = x0 + 13;
    if (x1 > NGB) x1 = NGB;
    float s = 0.f;
    for (int bx = x0; bx < x1; ++bx)
        s += statsbuf[(size_t)(by * NGB + bx) * 256 + is2 * 128 + cl];
    spart[b * 512 + t] = s;
}

// ---- stats reduce stage 2: finalize BN affine  A=gamma*inv, B=beta-mean*A
__global__ void k_statred2(const float* __restrict__ spart, const float* __restrict__ gamma,
                           const float* __restrict__ beta, float* __restrict__ Ap,
                           float* __restrict__ Bp) {
    int c = threadIdx.x;   // 256
    float s = 0.f, s2 = 0.f;
#pragma unroll 8
    for (int b = 0; b < 32; ++b) {
        s += spart[b * 512 + c];
        s2 += spart[b * 512 + 256 + c];
    }
    float mean = s * (1.f / N_NODES);
    float var = s2 * (1.f / N_NODES) - mean * mean;
    float inv = rsqrtf(var + 1e-5f);
    float A = gamma[c] * inv;
    Ap[c] = A;
    Bp[c] = beta[c] - mean * A;
}

// ---- graph mean-pool of relu(A*z+B) over slice-major z; ALSO writes h = relu(A*z+B)
// back IN PLACE (each element read once then overwritten) so agg stays plain-sum.
__global__ void k_pool(unsigned short* __restrict__ z, const float* __restrict__ Ap,
                       const float* __restrict__ Bp, const int* __restrict__ gstart,
                       float* __restrict__ partl) {
    int g = blockIdx.x, sp = blockIdx.y, t = threadIdx.x;
    float A = Ap[t], B = Bp[t];
    unsigned short* zp = z + (size_t)(t >> 5) * SLS + (t & 31);
    int beg = gstart[g], c = gstart[g + 1] - beg;
    int chunk = (c + 3) >> 2;
    int r0 = beg + sp * chunk;
    int r1 = beg + c;
    int rlim = r0 + chunk;
    if (rlim < r1) r1 = rlim;
    float a0 = 0.f, a1 = 0.f, a2 = 0.f, a3 = 0.f;
    int r = r0;
    for (; r + 4 <= r1; r += 4) {
        float v0 = fmaxf(fmaf(A, bf2f(zp[(size_t)r * 32]), B), 0.f);
        float v1 = fmaxf(fmaf(A, bf2f(zp[(size_t)(r + 1) * 32]), B), 0.f);
        float v2 = fmaxf(fmaf(A, bf2f(zp[(size_t)(r + 2) * 32]), B), 0.f);
        float v3 = fmaxf(fmaf(A, bf2f(zp[(size_t)(r + 3) * 32]), B), 0.f);
        zp[(size_t)r * 32] = f2bf(v0);
        zp[(size_t)(r + 1) * 32] = f2bf(v1);
        zp[(size_t)(r + 2) * 32] = f2bf(v2);
        zp[(size_t)(r + 3) * 32] = f2bf(v3);
        a0 += v0; a1 += v1; a2 += v2; a3 += v3;
    }
    for (; r < r1; ++r) {
        float v = fmaxf(fmaf(A, bf2f(zp[(size_t)r * 32]), B), 0.f);
        zp[(size_t)r * 32] = f2bf(v);
        a0 += v;
    }
    partl[(size_t)(g * 4 + sp) * 256 + t] = (a0 + a1) + (a2 + a3);
}

// ---- FC head: sums pool partials, divides by cnt, 2-layer MLP
__global__ __launch_bounds__(1024) void k_fc(const float* __restrict__ part,
                                             const int* __restrict__ gstart,
                                             const float* __restrict__ W1,
                                             const float* __restrict__ b1,
                                             const float* __restrict__ W2,
                                             const float* __restrict__ b2,
                                             float* __restrict__ out) {
    __shared__ float gs[DIM * NLAYERS];
    __shared__ float pt[8][128];
    __shared__ float red2[2];
    int g = blockIdx.x, t = threadIdx.x;
    float invc = 1.f / fmaxf((float)(gstart[g + 1] - gstart[g]), 1.f);
    for (int i = t; i < DIM * NLAYERS; i += 1024) {
        int l = i >> 8, c = i & 255;
        const float* pl = part + ((size_t)(l * NGRAPHS + g) * 4) * 256 + c;
        gs[i] = (pl[0] + pl[256] + pl[512] + pl[768]) * invc;
    }
    __syncthreads();
    int o = t & 127, kk = t >> 7;
    float acc = 0.f;
    const float* wp = W1 + (size_t)(kk * 96) * 128 + o;
#pragma unroll 4
    for (int k = 0; k < 96; ++k) acc = fmaf(gs[kk * 96 + k], wp[(size_t)k * 128], acc);
    pt[kk][o] = acc;
    __syncthreads();
    if (t < 128) {
        float v = b1[o];
#pragma unroll
        for (int p = 0; p < 8; ++p) v += pt[p][o];
        v = fmaxf(v, 0.f) * W2[o];
#pragma unroll
        for (int off = 32; off; off >>= 1) v += __shfl_down(v, off, 64);
        if ((t & 63) == 0) red2[t >> 6] = v;
    }
    __syncthreads();
    if (t == 0) out[g] = red2[0] + red2[1] + b2[0];
}

extern "C" void kernel_launch(void* const* d_in, const int* in_sizes, int n_in,
                              void* d_out, int out_size, void* d_ws, size_t ws_size,
                              hipStream_t stream) {
    const float* x = (const float*)d_in[0];
    const int* ei = (const int*)d_in[1];
    const int* batch = (const int*)d_in[2];
    const float* W_enc = (const float*)d_in[4];
    const float* b_enc = (const float*)d_in[5];
    const float* W1 = (const float*)d_in[6];
    const float* b1 = (const float*)d_in[7];
    const float* W2 = (const float*)d_in[8];
    const float* b2 = (const float*)d_in[9];
    const float* gamma = (const float*)d_in[10];
    const float* beta = (const float*)d_in[11];
    const float* Wfc1 = (const float*)d_in[12];
    const float* bfc1 = (const float*)d_in[13];
    const float* Wfc2 = (const float*)d_in[14];
    const float* bfc2 = (const float*)d_in[15];
    float* out = (float*)d_out;
    const int* srcp = ei;
    const int* dstp = ei + N_EDGES;

    // Workspace bump allocator (~108 MB)
    char* w = (char*)d_ws;
    auto alloc = [&](size_t b) -> char* {
        char* p = w;
        w += (b + 255) & ~(size_t)255;
        return p;
    };
    unsigned short* xb   = (unsigned short*)alloc((size_t)N_PAD * F_INPUT * 2);
    unsigned short* hbuf = (unsigned short*)alloc(8 * SLS * 2);  // enc out / z / h (in-place)
    unsigned short* zA   = (unsigned short*)alloc(8 * SLS * 2);  // agg out
    unsigned short* tbuf = (unsigned short*)alloc((size_t)N_PAD * DIM * 2);  // row-major MLP mid
    unsigned short* wench = (unsigned short*)alloc(F_INPUT * DIM * 2);
    unsigned short* wencl = (unsigned short*)alloc(F_INPUT * DIM * 2);
    unsigned short* w1h = (unsigned short*)alloc((size_t)NLAYERS * DIM * DIM * 2);
    unsigned short* w1l = (unsigned short*)alloc((size_t)NLAYERS * DIM * DIM * 2);
    unsigned short* w2h = (unsigned short*)alloc((size_t)NLAYERS * DIM * DIM * 2);
    unsigned short* w2l = (unsigned short*)alloc((size_t)NLAYERS * DIM * DIM * 2);
    unsigned short* csr16 = (unsigned short*)alloc((size_t)N_EDGES * 2);
    int* row_ptr = (int*)alloc((size_t)(N_NODES + 1) * 4);
    unsigned* slab = (unsigned*)alloc((size_t)NBH * 25000 * 4);
    int* deg = (int*)alloc((size_t)N_NODES * 4);
    int* perm = (int*)alloc((size_t)N_NODES * 4);
    int* gstart = (int*)alloc((NGRAPHS + 1) * 4);
    int* bsum = (int*)alloc(256 * 4);
    int* boff = (int*)alloc(256 * 4);
    int* dcnt = (int*)alloc(64 * 4);
    int* dcur = (int*)alloc(64 * 4);
    float* statsbuf = (float*)alloc((size_t)2 * NGB * 256 * 4);
    float* spart = (float*)alloc((size_t)32 * 512 * 4);
    float* Abn = (float*)alloc(256 * 4);
    float* Bbn = (float*)alloc(256 * 4);
    float* part = (float*)alloc((size_t)NLAYERS * NGRAPHS * 4 * 256 * 4);
    // basep (12.8 MB) aliases tbuf (25.6 MB): basep's lifetime ends before tbuf's first write
    int* basep = (int*)tbuf;

    hipMemsetAsync(dcnt, 0, 64 * 4, stream);

    // prep: weights hi/lo fragment-packed + x->bf16 (6250 blocks: x-conversion bound)
    k_prep<<<6250, 256, 0, stream>>>(W_enc, W1, W2, x, wench, wencl, w1h, w1l, w2h, w2l, xb);

    // CSR build (u16 indices) + degree-sorted perm, atomic-light
    const int NB = (N_NODES + 255) / 256;  // 196
    k_count<<<NBH, 512, 0, stream>>>(dstp, slab);
    k_degred<<<NB, 256, 0, stream>>>(slab, batch, deg, gstart);
    k_dhist<<<NB, 256, 0, stream>>>(deg, dcnt);
    k_dscan<<<1, 64, 0, stream>>>(dcnt, dcur);
    k_dfill<<<NB, 256, 0, stream>>>(deg, dcur, perm);
    k_scan1<<<NB, 256, 0, stream>>>(deg, row_ptr + 1, bsum);
    k_scan2<<<1, 256, 0, stream>>>(bsum, boff, NB);
    k_scan3<<<NB, 256, 0, stream>>>(row_ptr, boff);
    k_base<<<NB, 256, 0, stream>>>(slab, row_ptr, basep);
    k_fill2<<<NBH, 512, 0, stream>>>(srcp, dstp, basep, csr16);

    // encoder: h = x @ W_enc + b_enc  (A row-major, C slice-major -> hbuf)
    dim3 ggrid(NGB, 2);
    k_gemm<F_INPUT, false, true, false, false><<<ggrid, 256, 0, stream>>>(
        xb, wench, wencl, b_enc, hbuf, nullptr, N_NODES);

    dim3 pgrid(NGRAPHS, 4);
    const int AGRID = 782 * 8;
    for (int l = 0; l < NLAYERS; ++l) {
        // agg: plain sum, hbuf (h) -> zA
        k_agg<<<AGRID, 256, 0, stream>>>(hbuf, row_ptr, csr16, perm, zA);
        // GEMM-1: A slice-major (zA), C row-major (tbuf), relu
        k_gemm<DIM, true, false, true, false><<<ggrid, 256, 0, stream>>>(
            zA, w1h + l * 65536, w1l + l * 65536, b1 + l * DIM, tbuf, nullptr, N_NODES);
        // GEMM-2: A row-major (tbuf), C slice-major (hbuf = z), stats
        k_gemm<DIM, false, true, false, true><<<ggrid, 256, 0, stream>>>(
            tbuf, w2h + l * 65536, w2l + l * 65536, b2 + l * DIM, hbuf, statsbuf, N_NODES);
        k_statred1<<<32, 512, 0, stream>>>(statsbuf, spart);
        k_statred2<<<1, 256, 0, stream>>>(spart, gamma + l * DIM, beta + l * DIM, Abn, Bbn);
        // pool: reads z (hbuf), writes h back in place + graph partials
        k_pool<<<pgrid, 256, 0, stream>>>(hbuf, Abn, Bbn, gstart, part + (size_t)l * NGRAPHS * 4 * 256);
    }
    k_fc<<<NGRAPHS, 1024, 0, stream>>>(part, gstart, Wfc1, bfc1, Wfc2, bfc2, out);
}

// Round 11
// 571.120 us; speedup vs baseline: 1.2251x; 1.2251x over previous
//
#include <hip/hip_runtime.h>
#include <cstdint>
#include <cstddef>

// Problem constants (fixed by the reference setup)
#define N_NODES 50000
#define N_PAD   50048   // 391 * 128 = 782 * 64
#define N_EDGES 800000
#define F_INPUT 128
#define DIM 256
#define NLAYERS 3
#define NGRAPHS 512
#define NBH 64          // histogram/fill blocks
#define EPB 12500       // edges per histogram block
#define NMB 782         // 64-row blocks (N_PAD/64)
#define SLS ((size_t)N_PAD * 32)   // slice stride (elements), slice-major activations

typedef __bf16 bf16_t;
typedef bf16_t bf16x8 __attribute__((ext_vector_type(8)));
typedef float f32x4 __attribute__((ext_vector_type(4)));

__device__ __forceinline__ float bf2f(unsigned short u) {
    union { unsigned u32; float f; } x; x.u32 = ((unsigned)u) << 16; return x.f;
}
__device__ __forceinline__ unsigned short f2bf(float f) {
    union { float f; unsigned u; } x; x.f = f;
    unsigned r = (x.u + 0x7fffu + ((x.u >> 16) & 1u)) >> 16;
    return (unsigned short)r;
}

__device__ __forceinline__ void gl_lds16(const unsigned short* g, unsigned short* l) {
    __builtin_amdgcn_global_load_lds(
        (const __attribute__((address_space(1))) void*)g,
        (__attribute__((address_space(3))) void*)l, 16, 0, 0);
}

// MFMA-fragment-order packing for B (weights): wave fragment load = 64 lanes x 16B
// contiguous (1KB coalesced, L2-resident). Wave wid (n-range wid*64..+64) stream:
// base + wid*4*KS*512 + lane*8, fragment (j,ks) at +(j*KS+ks)*512.
__device__ __forceinline__ size_t frag_off(int n, int k, int K) {
    int nb = n >> 7, half = (n >> 6) & 1, j = (n >> 4) & 3, lm = n & 15;
    int ks = k >> 5, q = (k >> 3) & 3, e = k & 7;
    return ((size_t)(((nb * 2 + half) * 4 + j) * (K >> 5) + ks)) * 512 + (q * 16 + lm) * 8 + e;
}

// ---- merged prep: weight hi/lo split into fragment order AND x f32->bf16 (6250 blocks)
__global__ void k_prep(const float* __restrict__ W_enc, const float* __restrict__ W1,
                       const float* __restrict__ W2, const float* __restrict__ x,
                       unsigned short* __restrict__ wench, unsigned short* __restrict__ wencl,
                       unsigned short* __restrict__ w1h, unsigned short* __restrict__ w1l,
                       unsigned short* __restrict__ w2h, unsigned short* __restrict__ w2l,
                       unsigned short* __restrict__ xb) {
    int idx = blockIdx.x * 256 + threadIdx.x;
    if (idx < 32768) {                       // W_enc [128][256], K=128
        float w = W_enc[idx];
        int k = idx >> 8, n = idx & 255;
        unsigned short h = f2bf(w), lo = f2bf(w - bf2f(h));
        size_t o = frag_off(n, k, 128);
        wench[o] = h; wencl[o] = lo;
    } else if (idx < 32768 + 196608) {       // W1 [3][256][256], K=256
        int j = idx - 32768;
        int l = j >> 16, r = j & 65535, k = r >> 8, n = r & 255;
        float w = W1[j];
        unsigned short h = f2bf(w), lo = f2bf(w - bf2f(h));
        size_t o = (size_t)l * 65536 + frag_off(n, k, 256);
        w1h[o] = h; w1l[o] = lo;
    } else if (idx < 32768 + 2 * 196608) {   // W2
        int j = idx - 32768 - 196608;
        int l = j >> 16, r = j & 65535, k = r >> 8, n = r & 255;
        float w = W2[j];
        unsigned short h = f2bf(w), lo = f2bf(w - bf2f(h));
        size_t o = (size_t)l * 65536 + frag_off(n, k, 256);
        w2h[o] = h; w2l[o] = lo;
    }
    if (idx < (N_NODES * F_INPUT) / 4) {     // x -> bf16, 4 at a time
        float4 v = reinterpret_cast<const float4*>(x)[idx];
        ushort4 o;
        o.x = f2bf(v.x); o.y = f2bf(v.y); o.z = f2bf(v.z); o.w = f2bf(v.w);
        reinterpret_cast<ushort4*>(xb)[idx] = o;
    }
}

// ---- per-block LDS histogram of dst (packed 2x16-bit, 2 node-range passes)
__global__ __launch_bounds__(512) void k_count(const int* __restrict__ dst,
                                               unsigned* __restrict__ slab) {
    __shared__ unsigned bins[16384];
    int b = blockIdx.x, t = threadIdx.x;
    int e0 = b * EPB, e1 = e0 + EPB;
    for (int pass = 0; pass < 2; ++pass) {
        int lo = pass << 15;
        int words = pass ? 8616 : 16384;
        for (int w = t; w < 16384; w += 512) bins[w] = 0;
        __syncthreads();
        for (int e = e0 + t; e < e1; e += 512) {
            int r = dst[e] - lo;
            if ((unsigned)r < 32768u)
                atomicAdd(&bins[r >> 1], 1u << ((r & 1) * 16));
        }
        __syncthreads();
        unsigned* out = slab + b * 25000 + (pass ? 16384 : 0);
        for (int w = t; w < words; w += 512) out[w] = bins[w];
        __syncthreads();
    }
}

// ---- reduce count slabs -> deg; graph boundaries from sorted batch -> gstart
__global__ void k_degred(const unsigned* __restrict__ slab, const int* __restrict__ batch,
                         int* __restrict__ deg, int* __restrict__ gstart) {
    int i = blockIdx.x * 256 + threadIdx.x;
    if (i < 25000) {
        unsigned s = 0;
#pragma unroll 8
        for (int b = 0; b < NBH; ++b) s += slab[b * 25000 + i];
        deg[2 * i] = s & 0xffff;
        deg[2 * i + 1] = s >> 16;
    }
    if (i < N_NODES) {
        int bt = batch[i];
        int pb = (i == 0) ? -1 : batch[i - 1];
        if (bt != pb)
            for (int g = pb + 1; g <= bt; ++g) gstart[g] = i;
        if (i == N_NODES - 1)
            for (int g = bt + 1; g <= NGRAPHS; ++g) gstart[g] = N_NODES;
    }
}

// ---- scan step 1: per-block inclusive scan of deg
__global__ void k_scan1(const int* __restrict__ deg, int* __restrict__ rp1,
                        int* __restrict__ bsum) {
    __shared__ int s[256];
    int t = threadIdx.x, b = blockIdx.x, i = b * 256 + t;
    int v = (i < N_NODES) ? deg[i] : 0;
    s[t] = v; __syncthreads();
    for (int off = 1; off < 256; off <<= 1) {
        int x = (t >= off) ? s[t - off] : 0;
        __syncthreads(); s[t] += x; __syncthreads();
    }
    if (i < N_NODES) rp1[i] = s[t];
    if (t == 255) bsum[b] = s[255];
}

// ---- scan step 2: exclusive scan of block sums
__global__ void k_scan2(const int* __restrict__ bsum, int* __restrict__ boff, int nb) {
    __shared__ int s[256];
    int t = threadIdx.x;
    int v = (t < nb) ? bsum[t] : 0;
    s[t] = v; __syncthreads();
    for (int off = 1; off < 256; off <<= 1) {
        int x = (t >= off) ? s[t - off] : 0;
        __syncthreads(); s[t] += x; __syncthreads();
    }
    if (t < nb) boff[t] = s[t] - v;
}

// ---- scan step 3: add block offsets; finalize row_ptr[0]
__global__ void k_scan3(int* __restrict__ row_ptr, const int* __restrict__ boff) {
    int t = threadIdx.x, b = blockIdx.x, i = b * 256 + t;
    if (i < N_NODES) row_ptr[1 + i] += boff[b];
    if (i == 0) row_ptr[0] = 0;
}

// ---- per-(block,node) exclusive bases from count slabs
__global__ void k_base(const unsigned* __restrict__ slab, const int* __restrict__ row_ptr,
                       int* __restrict__ base) {
    int n = blockIdx.x * 256 + threadIdx.x;
    if (n >= N_NODES) return;
    int w = n >> 1, sh = (n & 1) * 16;
    int cur = row_ptr[n];
#pragma unroll 4
    for (int b = 0; b < NBH; ++b) {
        base[b * N_NODES + n] = cur;
        cur += (slab[b * 25000 + w] >> sh) & 0xffff;
    }
}

// ---- CSR fill with LDS cursors (no global atomics), u16 indices
__global__ __launch_bounds__(512) void k_fill2(const int* __restrict__ src,
                                               const int* __restrict__ dst,
                                               const int* __restrict__ base,
                                               unsigned short* __restrict__ csr16) {
    __shared__ unsigned bins[16384];
    int b = blockIdx.x, t = threadIdx.x;
    int e0 = b * EPB, e1 = e0 + EPB;
    for (int pass = 0; pass < 2; ++pass) {
        int lo = pass << 15;
        for (int w = t; w < 16384; w += 512) bins[w] = 0;
        __syncthreads();
        for (int e = e0 + t; e < e1; e += 512) {
            int d = dst[e];
            int r = d - lo;
            if ((unsigned)r < 32768u) {
                int sh = (r & 1) * 16;
                unsigned old = atomicAdd(&bins[r >> 1], 1u << sh);
                int local = (old >> sh) & 0xffff;
                csr16[base[b * N_NODES + d] + local] = (unsigned short)src[e];
            }
        }
        __syncthreads();
    }
}

// ---- XCD-sliced plain-sum aggregation (spatial node order — NO perm).
// slice = blockIdx.x & 7; one wave = 16 consecutive nodes x one slice.
__global__ void k_agg(const unsigned short* __restrict__ zin, const int* __restrict__ row_ptr,
                      const unsigned short* __restrict__ csr16,
                      unsigned short* __restrict__ z0) {
    int sl = blockIdx.x & 7;
    int wid = threadIdx.x >> 6, lane = threadIdx.x & 63;
    int g = lane >> 2, c = lane & 3;
    int node = (blockIdx.x >> 3) * 64 + wid * 16 + g;   // grid.x = 782*8
    bool valid = node < N_NODES;
    const unsigned short* table = zin + (size_t)sl * SLS;
    int e = 0, end = 0;
    if (valid) { e = row_ptr[node]; end = row_ptr[node + 1]; }
    float acc[8] = {0.f, 0.f, 0.f, 0.f, 0.f, 0.f, 0.f, 0.f};
    int srcn = (e < end) ? (int)csr16[e] : 0;
    while (e < end) {
        int cur = srcn;
        ++e;
        if (e < end) srcn = (int)csr16[e];
        uint4 v = *(const uint4*)(table + (size_t)cur * 32 + c * 8);
        const unsigned short* pv = (const unsigned short*)&v;
#pragma unroll
        for (int i = 0; i < 8; ++i) acc[i] += bf2f(pv[i]);
    }
    if (valid) {
        uint4 ov = *(const uint4*)(table + (size_t)node * 32 + c * 8);
        const unsigned short* po = (const unsigned short*)&ov;
        uint4 o;
        unsigned short* pw = (unsigned short*)&o;
#pragma unroll
        for (int i = 0; i < 8; ++i) pw[i] = f2bf(bf2f(po[i]) + acc[i]);
        *(uint4*)(z0 + (size_t)sl * SLS + (size_t)node * 32 + c * 8) = o;
    }
}

// ---- encoder GEMM: 64-row blocks, A dbuf-LDS-staged (coalesced DMA), B direct
// packed fragments, C slice-major. Wave wid owns cols [wid*64, wid*64+64).
__global__ __launch_bounds__(256) void k_enc(const unsigned short* __restrict__ A,
                                             const unsigned short* __restrict__ Whi,
                                             const unsigned short* __restrict__ Wlo,
                                             const float* __restrict__ bias,
                                             unsigned short* __restrict__ C) {
    constexpr int KS = 4;   // K = 128
    __shared__ __align__(16) unsigned short As[2][64 * 32];
    const int tid = threadIdx.x;
    const int m0 = blockIdx.x * 64;
    const int wid = tid >> 6, lane = tid & 63;
    const int lm = lane & 15, q = lane >> 4;
    const int sr = tid >> 2, sc = tid & 3;
    const unsigned short* fh = Whi + (size_t)wid * 4 * KS * 512 + lane * 8;
    const unsigned short* fl = Wlo + (size_t)wid * 4 * KS * 512 + lane * 8;

    f32x4 acc[4][4];
#pragma unroll
    for (int i = 0; i < 4; ++i)
#pragma unroll
        for (int j = 0; j < 4; ++j) acc[i][j] = (f32x4){0.f, 0.f, 0.f, 0.f};

    gl_lds16(A + (size_t)(m0 + sr) * 128 + sc * 8, &As[0][sr * 32 + sc * 8]);
    int p = 0;
    for (int ks = 0; ks < KS; ++ks) {
        __syncthreads();
        if (ks + 1 < KS)
            gl_lds16(A + (size_t)(m0 + sr) * 128 + (ks + 1) * 32 + sc * 8,
                     &As[p ^ 1][sr * 32 + sc * 8]);
        bf16x8 af[4], bh[4], bl[4];
#pragma unroll
        for (int j = 0; j < 4; ++j) {
            bh[j] = *reinterpret_cast<const bf16x8*>(fh + (j * KS + ks) * 512);
            bl[j] = *reinterpret_cast<const bf16x8*>(fl + (j * KS + ks) * 512);
        }
#pragma unroll
        for (int i = 0; i < 4; ++i)
            af[i] = *reinterpret_cast<const bf16x8*>(&As[p][(i * 16 + lm) * 32 + q * 8]);
#pragma unroll
        for (int i = 0; i < 4; ++i)
#pragma unroll
            for (int j = 0; j < 4; ++j) {
                acc[i][j] = __builtin_amdgcn_mfma_f32_16x16x32_bf16(af[i], bl[j], acc[i][j], 0, 0, 0);
                acc[i][j] = __builtin_amdgcn_mfma_f32_16x16x32_bf16(af[i], bh[j], acc[i][j], 0, 0, 0);
            }
        p ^= 1;
    }
#pragma unroll
    for (int j = 0; j < 4; ++j) {
        int col = wid * 64 + j * 16 + lm;
        float bv = bias[col];
        unsigned short* cp = C + (size_t)(col >> 5) * SLS + (col & 31);
#pragma unroll
        for (int i = 0; i < 4; ++i) {
            int row0 = m0 + i * 16 + q * 4;
#pragma unroll
            for (int r = 0; r < 4; ++r)
                cp[(size_t)(row0 + r) * 32] = f2bf(acc[i][j][r] + bv);
        }
    }
}

// ---- fused MLP: z0 @ W1 + b1 -> relu -> t (LDS) -> t @ W2 + b2 -> z + stats.
// 64-row blocks (grid 782), wave wid owns 64 cols in both GEMMs.
__global__ __launch_bounds__(256) void k_mlp(const unsigned short* __restrict__ Az,
                                             const unsigned short* __restrict__ W1h,
                                             const unsigned short* __restrict__ W1l,
                                             const float* __restrict__ b1,
                                             const unsigned short* __restrict__ W2h,
                                             const unsigned short* __restrict__ W2l,
                                             const float* __restrict__ b2,
                                             unsigned short* __restrict__ Z,
                                             float* __restrict__ statsbuf, int M) {
    constexpr int KS = 8;    // K = 256
    constexpr int TP = 264;  // t row pitch (bank-spread padding)
    __shared__ __align__(16) unsigned short As[2][64 * 32];   // 8 KB
    __shared__ __align__(16) unsigned short tls[64 * TP];     // 33.8 KB
    __shared__ float sts[2][256];                             // 2 KB
    const int tid = threadIdx.x;
    const int m0 = blockIdx.x * 64;
    const int wid = tid >> 6, lane = tid & 63;
    const int lm = lane & 15, q = lane >> 4;
    const int sr = tid >> 2, sc = tid & 3;
    const unsigned short* f1h = W1h + (size_t)wid * 4 * KS * 512 + lane * 8;
    const unsigned short* f1l = W1l + (size_t)wid * 4 * KS * 512 + lane * 8;
    const unsigned short* f2h = W2h + (size_t)wid * 4 * KS * 512 + lane * 8;
    const unsigned short* f2l = W2l + (size_t)wid * 4 * KS * 512 + lane * 8;

    f32x4 acc[4][4];
#pragma unroll
    for (int i = 0; i < 4; ++i)
#pragma unroll
        for (int j = 0; j < 4; ++j) acc[i][j] = (f32x4){0.f, 0.f, 0.f, 0.f};

    // GEMM-1: staged A (slice-major), fragment B
    gl_lds16(Az + (size_t)(m0 + sr) * 32 + sc * 8, &As[0][sr * 32 + sc * 8]);
    int p = 0;
    for (int ks = 0; ks < KS; ++ks) {
        __syncthreads();
        if (ks + 1 < KS)
            gl_lds16(Az + (size_t)(ks + 1) * SLS + (size_t)(m0 + sr) * 32 + sc * 8,
                     &As[p ^ 1][sr * 32 + sc * 8]);
        bf16x8 af[4], bh[4], bl[4];
#pragma unroll
        for (int j = 0; j < 4; ++j) {
            bh[j] = *reinterpret_cast<const bf16x8*>(f1h + (j * KS + ks) * 512);
            bl[j] = *reinterpret_cast<const bf16x8*>(f1l + (j * KS + ks) * 512);
        }
#pragma unroll
        for (int i = 0; i < 4; ++i)
            af[i] = *reinterpret_cast<const bf16x8*>(&As[p][(i * 16 + lm) * 32 + q * 8]);
#pragma unroll
        for (int i = 0; i < 4; ++i)
#pragma unroll
            for (int j = 0; j < 4; ++j) {
                acc[i][j] = __builtin_amdgcn_mfma_f32_16x16x32_bf16(af[i], bl[j], acc[i][j], 0, 0, 0);
                acc[i][j] = __builtin_amdgcn_mfma_f32_16x16x32_bf16(af[i], bh[j], acc[i][j], 0, 0, 0);
            }
        p ^= 1;
    }
    // epilogue-1: t = relu(acc + b1) -> LDS
#pragma unroll
    for (int j = 0; j < 4; ++j) {
        int col = wid * 64 + j * 16 + lm;
        float bv = b1[col];
#pragma unroll
        for (int i = 0; i < 4; ++i) {
            int r0 = i * 16 + q * 4;
#pragma unroll
            for (int r = 0; r < 4; ++r)
                tls[(r0 + r) * TP + col] = f2bf(fmaxf(acc[i][j][r] + bv, 0.f));
        }
    }
    __syncthreads();

    // GEMM-2: A-fragments from LDS t, fragment B
#pragma unroll
    for (int i = 0; i < 4; ++i)
#pragma unroll
        for (int j = 0; j < 4; ++j) acc[i][j] = (f32x4){0.f, 0.f, 0.f, 0.f};
#pragma unroll 2
    for (int ks = 0; ks < KS; ++ks) {
        bf16x8 af[4], bh[4], bl[4];
#pragma unroll
        for (int j = 0; j < 4; ++j) {
            bh[j] = *reinterpret_cast<const bf16x8*>(f2h + (j * KS + ks) * 512);
            bl[j] = *reinterpret_cast<const bf16x8*>(f2l + (j * KS + ks) * 512);
        }
#pragma unroll
        for (int i = 0; i < 4; ++i)
            af[i] = *reinterpret_cast<const bf16x8*>(&tls[(i * 16 + lm) * TP + ks * 32 + q * 8]);
#pragma unroll
        for (int i = 0; i < 4; ++i)
#pragma unroll
            for (int j = 0; j < 4; ++j) {
                acc[i][j] = __builtin_amdgcn_mfma_f32_16x16x32_bf16(af[i], bl[j], acc[i][j], 0, 0, 0);
                acc[i][j] = __builtin_amdgcn_mfma_f32_16x16x32_bf16(af[i], bh[j], acc[i][j], 0, 0, 0);
            }
    }
    // epilogue-2: z = acc + b2 (slice-major) + fused column stats
#pragma unroll
    for (int j = 0; j < 4; ++j) {
        int col = wid * 64 + j * 16 + lm;
        float bv = b2[col];
        unsigned short* cp = Z + (size_t)(col >> 5) * SLS + (col & 31);
        float s = 0.f, s2 = 0.f;
#pragma unroll
        for (int i = 0; i < 4; ++i) {
            int row0 = m0 + i * 16 + q * 4;
#pragma unroll
            for (int r = 0; r < 4; ++r) {
                int row = row0 + r;
                if (row < M) {
                    float v = acc[i][j][r] + bv;
                    s += v; s2 = fmaf(v, v, s2);
                    cp[(size_t)row * 32] = f2bf(v);
                }
            }
        }
        s += __shfl_xor(s, 16); s += __shfl_xor(s, 32);
        s2 += __shfl_xor(s2, 16); s2 += __shfl_xor(s2, 32);
        if (q == 0) { sts[0][col] = s; sts[1][col] = s2; }
    }
    __syncthreads();
    if (tid < 256)
        statsbuf[(size_t)blockIdx.x * 512 + tid] = sts[0][tid];
    else if (tid < 512) { }
    if (tid < 256)
        statsbuf[(size_t)blockIdx.x * 512 + 256 + tid] = sts[1][tid];
}

// ---- stats reduce stage 1: 32 blocks x 512 thr over 782 block-slabs
__global__ __launch_bounds__(512) void k_statred1(const float* __restrict__ statsbuf,
                                                  float* __restrict__ spart) {
    int b = blockIdx.x, t = threadIdx.x;
    int x0 = b * 25, x1 = x0 + 25;
    if (x1 > NMB) x1 = NMB;
    float s = 0.f;
    for (int bx = x0; bx < x1; ++bx)
        s += statsbuf[(size_t)bx * 512 + t];
    spart[b * 512 + t] = s;
}

// ---- stats reduce stage 2: finalize BN affine  A=gamma*inv, B=beta-mean*A
__global__ void k_statred2(const float* __restrict__ spart, const float* __restrict__ gamma,
                           const float* __restrict__ beta, float* __restrict__ Ap,
                           float* __restrict__ Bp) {
    int c = threadIdx.x;   // 256
    float s = 0.f, s2 = 0.f;
#pragma unroll 8
    for (int b = 0; b < 32; ++b) {
        s += spart[b * 512 + c];
        s2 += spart[b * 512 + 256 + c];
    }
    float mean = s * (1.f / N_NODES);
    float var = s2 * (1.f / N_NODES) - mean * mean;
    float inv = rsqrtf(var + 1e-5f);
    float A = gamma[c] * inv;
    Ap[c] = A;
    Bp[c] = beta[c] - mean * A;
}

// ---- graph mean-pool of relu(A*z+B); writes h back IN PLACE
__global__ void k_pool(unsigned short* __restrict__ z, const float* __restrict__ Ap,
                       const float* __restrict__ Bp, const int* __restrict__ gstart,
                       float* __restrict__ partl) {
    int g = blockIdx.x, sp = blockIdx.y, t = threadIdx.x;
    float A = Ap[t], B = Bp[t];
    unsigned short* zp = z + (size_t)(t >> 5) * SLS + (t & 31);
    int beg = gstart[g], c = gstart[g + 1] - beg;
    int chunk = (c + 3) >> 2;
    int r0 = beg + sp * chunk;
    int r1 = beg + c;
    int rlim = r0 + chunk;
    if (rlim < r1) r1 = rlim;
    float a0 = 0.f, a1 = 0.f, a2 = 0.f, a3 = 0.f;
    int r = r0;
    for (; r + 4 <= r1; r += 4) {
        float v0 = fmaxf(fmaf(A, bf2f(zp[(size_t)r * 32]), B), 0.f);
        float v1 = fmaxf(fmaf(A, bf2f(zp[(size_t)(r + 1) * 32]), B), 0.f);
        float v2 = fmaxf(fmaf(A, bf2f(zp[(size_t)(r + 2) * 32]), B), 0.f);
        float v3 = fmaxf(fmaf(A, bf2f(zp[(size_t)(r + 3) * 32]), B), 0.f);
        zp[(size_t)r * 32] = f2bf(v0);
        zp[(size_t)(r + 1) * 32] = f2bf(v1);
        zp[(size_t)(r + 2) * 32] = f2bf(v2);
        zp[(size_t)(r + 3) * 32] = f2bf(v3);
        a0 += v0; a1 += v1; a2 += v2; a3 += v3;
    }
    for (; r < r1; ++r) {
        float v = fmaxf(fmaf(A, bf2f(zp[(size_t)r * 32]), B), 0.f);
        zp[(size_t)r * 32] = f2bf(v);
        a0 += v;
    }
    partl[(size_t)(g * 4 + sp) * 256 + t] = (a0 + a1) + (a2 + a3);
}

// ---- FC head: sums pool partials, divides by cnt, 2-layer MLP
__global__ __launch_bounds__(1024) void k_fc(const float* __restrict__ part,
                                             const int* __restrict__ gstart,
                                             const float* __restrict__ W1,
                                             const float* __restrict__ b1,
                                             const float* __restrict__ W2,
                                             const float* __restrict__ b2,
                                             float* __restrict__ out) {
    __shared__ float gs[DIM * NLAYERS];
    __shared__ float pt[8][128];
    __shared__ float red2[2];
    int g = blockIdx.x, t = threadIdx.x;
    float invc = 1.f / fmaxf((float)(gstart[g + 1] - gstart[g]), 1.f);
    for (int i = t; i < DIM * NLAYERS; i += 1024) {
        int l = i >> 8, c = i & 255;
        const float* pl = part + ((size_t)(l * NGRAPHS + g) * 4) * 256 + c;
        gs[i] = (pl[0] + pl[256] + pl[512] + pl[768]) * invc;
    }
    __syncthreads();
    int o = t & 127, kk = t >> 7;
    float acc = 0.f;
    const float* wp = W1 + (size_t)(kk * 96) * 128 + o;
#pragma unroll 4
    for (int k = 0; k < 96; ++k) acc = fmaf(gs[kk * 96 + k], wp[(size_t)k * 128], acc);
    pt[kk][o] = acc;
    __syncthreads();
    if (t < 128) {
        float v = b1[o];
#pragma unroll
        for (int p = 0; p < 8; ++p) v += pt[p][o];
        v = fmaxf(v, 0.f) * W2[o];
#pragma unroll
        for (int off = 32; off; off >>= 1) v += __shfl_down(v, off, 64);
        if ((t & 63) == 0) red2[t >> 6] = v;
    }
    __syncthreads();
    if (t == 0) out[g] = red2[0] + red2[1] + b2[0];
}

extern "C" void kernel_launch(void* const* d_in, const int* in_sizes, int n_in,
                              void* d_out, int out_size, void* d_ws, size_t ws_size,
                              hipStream_t stream) {
    const float* x = (const float*)d_in[0];
    const int* ei = (const int*)d_in[1];
    const int* batch = (const int*)d_in[2];
    const float* W_enc = (const float*)d_in[4];
    const float* b_enc = (const float*)d_in[5];
    const float* W1 = (const float*)d_in[6];
    const float* b1 = (const float*)d_in[7];
    const float* W2 = (const float*)d_in[8];
    const float* b2 = (const float*)d_in[9];
    const float* gamma = (const float*)d_in[10];
    const float* beta = (const float*)d_in[11];
    const float* Wfc1 = (const float*)d_in[12];
    const float* bfc1 = (const float*)d_in[13];
    const float* Wfc2 = (const float*)d_in[14];
    const float* bfc2 = (const float*)d_in[15];
    float* out = (float*)d_out;
    const int* srcp = ei;
    const int* dstp = ei + N_EDGES;

    // Workspace bump allocator (~92 MB)
    char* w = (char*)d_ws;
    auto alloc = [&](size_t b) -> char* {
        char* p = w;
        w += (b + 255) & ~(size_t)255;
        return p;
    };
    unsigned short* xb   = (unsigned short*)alloc((size_t)N_PAD * F_INPUT * 2);
    unsigned short* hbuf = (unsigned short*)alloc(8 * SLS * 2);  // enc out / z / h (in-place)
    unsigned short* zA   = (unsigned short*)alloc(8 * SLS * 2);  // agg out
    unsigned short* wench = (unsigned short*)alloc(F_INPUT * DIM * 2);
    unsigned short* wencl = (unsigned short*)alloc(F_INPUT * DIM * 2);
    unsigned short* w1h = (unsigned short*)alloc((size_t)NLAYERS * DIM * DIM * 2);
    unsigned short* w1l = (unsigned short*)alloc((size_t)NLAYERS * DIM * DIM * 2);
    unsigned short* w2h = (unsigned short*)alloc((size_t)NLAYERS * DIM * DIM * 2);
    unsigned short* w2l = (unsigned short*)alloc((size_t)NLAYERS * DIM * DIM * 2);
    unsigned short* csr16 = (unsigned short*)alloc((size_t)N_EDGES * 2);
    int* row_ptr = (int*)alloc((size_t)(N_NODES + 1) * 4);
    unsigned* slab = (unsigned*)alloc((size_t)NBH * 25000 * 4);
    int* deg = (int*)alloc((size_t)N_NODES * 4);
    int* basep = (int*)alloc((size_t)NBH * N_NODES * 4);
    int* gstart = (int*)alloc((NGRAPHS + 1) * 4);
    int* bsum = (int*)alloc(256 * 4);
    int* boff = (int*)alloc(256 * 4);
    float* statsbuf = (float*)alloc((size_t)NMB * 512 * 4);
    float* spart = (float*)alloc((size_t)32 * 512 * 4);
    float* Abn = (float*)alloc(256 * 4);
    float* Bbn = (float*)alloc(256 * 4);
    float* part = (float*)alloc((size_t)NLAYERS * NGRAPHS * 4 * 256 * 4);

    // prep: weights hi/lo fragment-packed + x->bf16 (6250 blocks: x-conversion bound)
    k_prep<<<6250, 256, 0, stream>>>(W_enc, W1, W2, x, wench, wencl, w1h, w1l, w2h, w2l, xb);

    // CSR build (u16 indices), atomic-free
    const int NB = (N_NODES + 255) / 256;  // 196
    k_count<<<NBH, 512, 0, stream>>>(dstp, slab);
    k_degred<<<NB, 256, 0, stream>>>(slab, batch, deg, gstart);
    k_scan1<<<NB, 256, 0, stream>>>(deg, row_ptr + 1, bsum);
    k_scan2<<<1, 256, 0, stream>>>(bsum, boff, NB);
    k_scan3<<<NB, 256, 0, stream>>>(row_ptr, boff);
    k_base<<<NB, 256, 0, stream>>>(slab, row_ptr, basep);
    k_fill2<<<NBH, 512, 0, stream>>>(srcp, dstp, basep, csr16);

    // encoder: h = x @ W_enc + b_enc -> hbuf (slice-major)
    k_enc<<<NMB, 256, 0, stream>>>(xb, wench, wencl, b_enc, hbuf);

    dim3 pgrid(NGRAPHS, 4);
    const int AGRID = 782 * 8;
    for (int l = 0; l < NLAYERS; ++l) {
        k_agg<<<AGRID, 256, 0, stream>>>(hbuf, row_ptr, csr16, zA);
        k_mlp<<<NMB, 256, 0, stream>>>(zA, w1h + l * 65536, w1l + l * 65536, b1 + l * DIM,
                                       w2h + l * 65536, w2l + l * 65536, b2 + l * DIM,
                                       hbuf, statsbuf, N_NODES);
        k_statred1<<<32, 512, 0, stream>>>(statsbuf, spart);
        k_statred2<<<1, 256, 0, stream>>>(spart, gamma + l * DIM, beta + l * DIM, Abn, Bbn);
        k_pool<<<pgrid, 256, 0, stream>>>(hbuf, Abn, Bbn, gstart, part + (size_t)l * NGRAPHS * 4 * 256);
    }
    k_fc<<<NGRAPHS, 1024, 0, stream>>>(part, gstart, Wfc1, bfc1, Wfc2, bfc2, out);
}

// Round 12
// 533.936 us; speedup vs baseline: 1.3104x; 1.0696x over previous
//
#include <hip/hip_runtime.h>
#include <cstdint>
#include <cstddef>

// Problem constants (fixed by the reference setup)
#define N_NODES 50000
#define N_PAD   50048   // 391 * 128 = 782 * 64
#define N_EDGES 800000
#define F_INPUT 128
#define DIM 256
#define NLAYERS 3
#define NGRAPHS 512
#define NBH 64          // histogram/fill blocks
#define EPB 12500       // edges per histogram block
#define NMB 782         // 64-row blocks (N_PAD/64)
#define SLS ((size_t)N_PAD * 32)   // slice stride (elements), slice-major activations

typedef __bf16 bf16_t;
typedef bf16_t bf16x8 __attribute__((ext_vector_type(8)));
typedef float f32x4 __attribute__((ext_vector_type(4)));

__device__ __forceinline__ float bf2f(unsigned short u) {
    union { unsigned u32; float f; } x; x.u32 = ((unsigned)u) << 16; return x.f;
}
__device__ __forceinline__ unsigned short f2bf(float f) {
    union { float f; unsigned u; } x; x.f = f;
    unsigned r = (x.u + 0x7fffu + ((x.u >> 16) & 1u)) >> 16;
    return (unsigned short)r;
}

__device__ __forceinline__ void gl_lds16(const unsigned short* g, unsigned short* l) {
    __builtin_amdgcn_global_load_lds(
        (const __attribute__((address_space(1))) void*)g,
        (__attribute__((address_space(3))) void*)l, 16, 0, 0);
}

// MFMA-fragment-order packing for B (weights): wave fragment load = 64 lanes x 16B
// contiguous (1KB coalesced, L2-resident).
__device__ __forceinline__ size_t frag_off(int n, int k, int K) {
    int nb = n >> 7, half = (n >> 6) & 1, j = (n >> 4) & 3, lm = n & 15;
    int ks = k >> 5, q = (k >> 3) & 3, e = k & 7;
    return ((size_t)(((nb * 2 + half) * 4 + j) * (K >> 5) + ks)) * 512 + (q * 16 + lm) * 8 + e;
}

// ---- merged prep: weight hi/lo frag-packed; x f32->bf16 into SLICE-MAJOR [4][N_PAD][32]
__global__ void k_prep(const float* __restrict__ W_enc, const float* __restrict__ W1,
                       const float* __restrict__ W2, const float* __restrict__ x,
                       unsigned short* __restrict__ wench, unsigned short* __restrict__ wencl,
                       unsigned short* __restrict__ w1h, unsigned short* __restrict__ w1l,
                       unsigned short* __restrict__ w2h, unsigned short* __restrict__ w2l,
                       unsigned short* __restrict__ xb) {
    int idx = blockIdx.x * 256 + threadIdx.x;
    if (idx < 32768) {                       // W_enc [128][256], K=128
        float w = W_enc[idx];
        int k = idx >> 8, n = idx & 255;
        unsigned short h = f2bf(w), lo = f2bf(w - bf2f(h));
        size_t o = frag_off(n, k, 128);
        wench[o] = h; wencl[o] = lo;
    } else if (idx < 32768 + 196608) {       // W1 [3][256][256], K=256
        int j = idx - 32768;
        int l = j >> 16, r = j & 65535, k = r >> 8, n = r & 255;
        float w = W1[j];
        unsigned short h = f2bf(w), lo = f2bf(w - bf2f(h));
        size_t o = (size_t)l * 65536 + frag_off(n, k, 256);
        w1h[o] = h; w1l[o] = lo;
    } else if (idx < 32768 + 2 * 196608) {   // W2
        int j = idx - 32768 - 196608;
        int l = j >> 16, r = j & 65535, k = r >> 8, n = r & 255;
        float w = W2[j];
        unsigned short h = f2bf(w), lo = f2bf(w - bf2f(h));
        size_t o = (size_t)l * 65536 + frag_off(n, k, 256);
        w2h[o] = h; w2l[o] = lo;
    }
    if (idx < (N_NODES * F_INPUT) / 4) {     // x -> bf16 slice-major, 4 chans at a time
        float4 v = reinterpret_cast<const float4*>(x)[idx];
        ushort4 o;
        o.x = f2bf(v.x); o.y = f2bf(v.y); o.z = f2bf(v.z); o.w = f2bf(v.w);
        int n = idx >> 5, f0 = (idx & 31) * 4;
        *reinterpret_cast<ushort4*>(xb + (size_t)(f0 >> 5) * SLS + (size_t)n * 32 + (f0 & 31)) = o;
    }
}

// ---- per-block LDS histogram of dst (packed 2x16-bit, 2 node-range passes)
__global__ __launch_bounds__(512) void k_count(const int* __restrict__ dst,
                                               unsigned* __restrict__ slab) {
    __shared__ unsigned bins[16384];
    int b = blockIdx.x, t = threadIdx.x;
    int e0 = b * EPB, e1 = e0 + EPB;
    for (int pass = 0; pass < 2; ++pass) {
        int lo = pass << 15;
        int words = pass ? 8616 : 16384;
        for (int w = t; w < 16384; w += 512) bins[w] = 0;
        __syncthreads();
        for (int e = e0 + t; e < e1; e += 512) {
            int r = dst[e] - lo;
            if ((unsigned)r < 32768u)
                atomicAdd(&bins[r >> 1], 1u << ((r & 1) * 16));
        }
        __syncthreads();
        unsigned* out = slab + b * 25000 + (pass ? 16384 : 0);
        for (int w = t; w < words; w += 512) out[w] = bins[w];
        __syncthreads();
    }
}

// ---- reduce count slabs -> deg; graph boundaries from sorted batch -> gstart
__global__ void k_degred(const unsigned* __restrict__ slab, const int* __restrict__ batch,
                         int* __restrict__ deg, int* __restrict__ gstart) {
    int i = blockIdx.x * 256 + threadIdx.x;
    if (i < 25000) {
        unsigned s = 0;
#pragma unroll 8
        for (int b = 0; b < NBH; ++b) s += slab[b * 25000 + i];
        deg[2 * i] = s & 0xffff;
        deg[2 * i + 1] = s >> 16;
    }
    if (i < N_NODES) {
        int bt = batch[i];
        int pb = (i == 0) ? -1 : batch[i - 1];
        if (bt != pb)
            for (int g = pb + 1; g <= bt; ++g) gstart[g] = i;
        if (i == N_NODES - 1)
            for (int g = bt + 1; g <= NGRAPHS; ++g) gstart[g] = N_NODES;
    }
}

// ---- scan step 1: per-block inclusive scan of deg
__global__ void k_scan1(const int* __restrict__ deg, int* __restrict__ rp1,
                        int* __restrict__ bsum) {
    __shared__ int s[256];
    int t = threadIdx.x, b = blockIdx.x, i = b * 256 + t;
    int v = (i < N_NODES) ? deg[i] : 0;
    s[t] = v; __syncthreads();
    for (int off = 1; off < 256; off <<= 1) {
        int x = (t >= off) ? s[t - off] : 0;
        __syncthreads(); s[t] += x; __syncthreads();
    }
    if (i < N_NODES) rp1[i] = s[t];
    if (t == 255) bsum[b] = s[255];
}

// ---- scan step 2: exclusive scan of block sums
__global__ void k_scan2(const int* __restrict__ bsum, int* __restrict__ boff, int nb) {
    __shared__ int s[256];
    int t = threadIdx.x;
    int v = (t < nb) ? bsum[t] : 0;
    s[t] = v; __syncthreads();
    for (int off = 1; off < 256; off <<= 1) {
        int x = (t >= off) ? s[t - off] : 0;
        __syncthreads(); s[t] += x; __syncthreads();
    }
    if (t < nb) boff[t] = s[t] - v;
}

// ---- scan step 3: add block offsets; finalize row_ptr[0]
__global__ void k_scan3(int* __restrict__ row_ptr, const int* __restrict__ boff) {
    int t = threadIdx.x, b = blockIdx.x, i = b * 256 + t;
    if (i < N_NODES) row_ptr[1 + i] += boff[b];
    if (i == 0) row_ptr[0] = 0;
}

// ---- per-(block,node) exclusive bases from count slabs
__global__ void k_base(const unsigned* __restrict__ slab, const int* __restrict__ row_ptr,
                       int* __restrict__ base) {
    int n = blockIdx.x * 256 + threadIdx.x;
    if (n >= N_NODES) return;
    int w = n >> 1, sh = (n & 1) * 16;
    int cur = row_ptr[n];
#pragma unroll 4
    for (int b = 0; b < NBH; ++b) {
        base[b * N_NODES + n] = cur;
        cur += (slab[b * 25000 + w] >> sh) & 0xffff;
    }
}

// ---- CSR fill with LDS cursors (no global atomics), u16 indices
__global__ __launch_bounds__(512) void k_fill2(const int* __restrict__ src,
                                               const int* __restrict__ dst,
                                               const int* __restrict__ base,
                                               unsigned short* __restrict__ csr16) {
    __shared__ unsigned bins[16384];
    int b = blockIdx.x, t = threadIdx.x;
    int e0 = b * EPB, e1 = e0 + EPB;
    for (int pass = 0; pass < 2; ++pass) {
        int lo = pass << 15;
        for (int w = t; w < 16384; w += 512) bins[w] = 0;
        __syncthreads();
        for (int e = e0 + t; e < e1; e += 512) {
            int d = dst[e];
            int r = d - lo;
            if ((unsigned)r < 32768u) {
                int sh = (r & 1) * 16;
                unsigned old = atomicAdd(&bins[r >> 1], 1u << sh);
                int local = (old >> sh) & 0xffff;
                csr16[base[b * N_NODES + d] + local] = (unsigned short)src[e];
            }
        }
        __syncthreads();
    }
}

// ---- XCD-sliced plain-sum aggregation (spatial node order).
// slice = blockIdx.x & 7; one wave = 16 consecutive nodes x one slice.
__global__ void k_agg(const unsigned short* __restrict__ zin, const int* __restrict__ row_ptr,
                      const unsigned short* __restrict__ csr16,
                      unsigned short* __restrict__ z0) {
    int sl = blockIdx.x & 7;
    int wid = threadIdx.x >> 6, lane = threadIdx.x & 63;
    int g = lane >> 2, c = lane & 3;
    int node = (blockIdx.x >> 3) * 64 + wid * 16 + g;   // grid.x = 782*8
    bool valid = node < N_NODES;
    const unsigned short* table = zin + (size_t)sl * SLS;
    int e = 0, end = 0;
    if (valid) { e = row_ptr[node]; end = row_ptr[node + 1]; }
    float acc[8] = {0.f, 0.f, 0.f, 0.f, 0.f, 0.f, 0.f, 0.f};
    int srcn = (e < end) ? (int)csr16[e] : 0;
    while (e < end) {
        int cur = srcn;
        ++e;
        if (e < end) srcn = (int)csr16[e];
        uint4 v = *(const uint4*)(table + (size_t)cur * 32 + c * 8);
        const unsigned short* pv = (const unsigned short*)&v;
#pragma unroll
        for (int i = 0; i < 8; ++i) acc[i] += bf2f(pv[i]);
    }
    if (valid) {
        uint4 ov = *(const uint4*)(table + (size_t)node * 32 + c * 8);
        const unsigned short* po = (const unsigned short*)&ov;
        uint4 o;
        unsigned short* pw = (unsigned short*)&o;
#pragma unroll
        for (int i = 0; i < 8; ++i) pw[i] = f2bf(bf2f(po[i]) + acc[i]);
        *(uint4*)(z0 + (size_t)sl * SLS + (size_t)node * 32 + c * 8) = o;
    }
}

// ---- encoder GEMM: 64-row blocks. A DMA'd in FRAGMENT order (conflict-free reads),
// B direct packed fragments, C via LDS -> vectorized uint4 global stores.
__global__ __launch_bounds__(256) void k_enc(const unsigned short* __restrict__ A,
                                             const unsigned short* __restrict__ Whi,
                                             const unsigned short* __restrict__ Wlo,
                                             const float* __restrict__ bias,
                                             unsigned short* __restrict__ C) {
    constexpr int KS = 4;   // K = 128
    __shared__ __align__(16) unsigned short As[2][2048];   // fragment order, 4KB each
    __shared__ __align__(16) unsigned short tls[16384];    // z staging, 32KB
    const int tid = threadIdx.x;
    const int m0 = blockIdx.x * 64;
    const int wid = tid >> 6, lane = tid & 63;
    const int lm = lane & 15, q = lane >> 4;
    const int drow = (tid >> 6) * 16 + (tid & 15);   // DMA row
    const int dq = (tid >> 4) & 3;                   // DMA k-chunk
    const unsigned short* fh = Whi + (size_t)wid * 4 * KS * 512 + lane * 8;
    const unsigned short* fl = Wlo + (size_t)wid * 4 * KS * 512 + lane * 8;

    f32x4 acc[4][4];
#pragma unroll
    for (int i = 0; i < 4; ++i)
#pragma unroll
        for (int j = 0; j < 4; ++j) acc[i][j] = (f32x4){0.f, 0.f, 0.f, 0.f};

    gl_lds16(A + (size_t)(m0 + drow) * 32 + dq * 8, &As[0][tid * 8]);
    int p = 0;
    for (int ks = 0; ks < KS; ++ks) {
        __syncthreads();
        if (ks + 1 < KS)
            gl_lds16(A + (size_t)(ks + 1) * SLS + (size_t)(m0 + drow) * 32 + dq * 8,
                     &As[p ^ 1][tid * 8]);
        bf16x8 af[4], bh[4], bl[4];
#pragma unroll
        for (int j = 0; j < 4; ++j) {
            bh[j] = *reinterpret_cast<const bf16x8*>(fh + (j * KS + ks) * 512);
            bl[j] = *reinterpret_cast<const bf16x8*>(fl + (j * KS + ks) * 512);
        }
#pragma unroll
        for (int i = 0; i < 4; ++i)
            af[i] = *reinterpret_cast<const bf16x8*>(&As[p][(i * 64 + lane) * 8]);
#pragma unroll
        for (int i = 0; i < 4; ++i)
#pragma unroll
            for (int j = 0; j < 4; ++j) {
                acc[i][j] = __builtin_amdgcn_mfma_f32_16x16x32_bf16(af[i], bl[j], acc[i][j], 0, 0, 0);
                acc[i][j] = __builtin_amdgcn_mfma_f32_16x16x32_bf16(af[i], bh[j], acc[i][j], 0, 0, 0);
            }
        p ^= 1;
    }
    __syncthreads();
    // stage C into LDS slice-major-local [sl][row][ch]
#pragma unroll
    for (int j = 0; j < 4; ++j) {
        int col = wid * 64 + j * 16 + lm;
        float bv = bias[col];
#pragma unroll
        for (int i = 0; i < 4; ++i) {
#pragma unroll
            for (int r = 0; r < 4; ++r)
                tls[(col >> 5) * 2048 + (i * 16 + q * 4 + r) * 32 + (col & 31)] =
                    f2bf(acc[i][j][r] + bv);
        }
    }
    __syncthreads();
#pragma unroll
    for (int c0 = 0; c0 < 8; ++c0) {
        int o = (c0 * 256 + tid) * 8;
        int sl = o >> 11;
        uint4 v = *reinterpret_cast<const uint4*>(&tls[o]);
        *reinterpret_cast<uint4*>(C + (size_t)sl * SLS + (size_t)m0 * 32 + (o - (sl << 11))) = v;
    }
}

// ---- fused MLP: z0 @ W1 + b1 -> relu -> t (LDS, fragment order) -> t @ W2 + b2
// -> z (LDS -> vectorized stores) + fused stats (per-wave direct global).
// LDS = 8KB As + 32KB tls = 40KB -> 4 blocks/CU.
__global__ __launch_bounds__(256) void k_mlp(const unsigned short* __restrict__ Az,
                                             const unsigned short* __restrict__ W1h,
                                             const unsigned short* __restrict__ W1l,
                                             const float* __restrict__ b1,
                                             const unsigned short* __restrict__ W2h,
                                             const unsigned short* __restrict__ W2l,
                                             const float* __restrict__ b2,
                                             unsigned short* __restrict__ Z,
                                             float* __restrict__ statsbuf, int M) {
    constexpr int KS = 8;    // K = 256
    __shared__ __align__(16) unsigned short As[2][2048];   // fragment order, 4KB each
    __shared__ __align__(16) unsigned short tls[16384];    // t / z staging, 32KB
    const int tid = threadIdx.x;
    const int m0 = blockIdx.x * 64;
    const int wid = tid >> 6, lane = tid & 63;
    const int lm = lane & 15, q = lane >> 4;
    const int drow = (tid >> 6) * 16 + (tid & 15);
    const int dq = (tid >> 4) & 3;
    const unsigned short* f1h = W1h + (size_t)wid * 4 * KS * 512 + lane * 8;
    const unsigned short* f1l = W1l + (size_t)wid * 4 * KS * 512 + lane * 8;
    const unsigned short* f2h = W2h + (size_t)wid * 4 * KS * 512 + lane * 8;
    const unsigned short* f2l = W2l + (size_t)wid * 4 * KS * 512 + lane * 8;

    f32x4 acc[4][4];
#pragma unroll
    for (int i = 0; i < 4; ++i)
#pragma unroll
        for (int j = 0; j < 4; ++j) acc[i][j] = (f32x4){0.f, 0.f, 0.f, 0.f};

    // GEMM-1: fragment-order staged A (slice-major source), fragment B
    gl_lds16(Az + (size_t)(m0 + drow) * 32 + dq * 8, &As[0][tid * 8]);
    int p = 0;
    for (int ks = 0; ks < KS; ++ks) {
        __syncthreads();
        if (ks + 1 < KS)
            gl_lds16(Az + (size_t)(ks + 1) * SLS + (size_t)(m0 + drow) * 32 + dq * 8,
                     &As[p ^ 1][tid * 8]);
        bf16x8 af[4], bh[4], bl[4];
#pragma unroll
        for (int j = 0; j < 4; ++j) {
            bh[j] = *reinterpret_cast<const bf16x8*>(f1h + (j * KS + ks) * 512);
            bl[j] = *reinterpret_cast<const bf16x8*>(f1l + (j * KS + ks) * 512);
        }
#pragma unroll
        for (int i = 0; i < 4; ++i)
            af[i] = *reinterpret_cast<const bf16x8*>(&As[p][(i * 64 + lane) * 8]);
#pragma unroll
        for (int i = 0; i < 4; ++i)
#pragma unroll
            for (int j = 0; j < 4; ++j) {
                acc[i][j] = __builtin_amdgcn_mfma_f32_16x16x32_bf16(af[i], bl[j], acc[i][j], 0, 0, 0);
                acc[i][j] = __builtin_amdgcn_mfma_f32_16x16x32_bf16(af[i], bh[j], acc[i][j], 0, 0, 0);
            }
        p ^= 1;
    }
    __syncthreads();
    // epilogue-1: t = relu(acc + b1) -> tls in FRAGMENT order [i2][ks2][lane2][e2]
#pragma unroll
    for (int j = 0; j < 4; ++j) {
        int col = wid * 64 + j * 16 + lm;
        float bv = b1[col];
        int ks2 = col >> 5;
        int q2 = (col >> 3) & 3;
        int e2 = col & 7;
#pragma unroll
        for (int i = 0; i < 4; ++i) {
#pragma unroll
            for (int r = 0; r < 4; ++r)
                tls[((i * 8 + ks2) * 64 + q2 * 16 + q * 4 + r) * 8 + e2] =
                    f2bf(fmaxf(acc[i][j][r] + bv, 0.f));
        }
    }
    __syncthreads();

    // GEMM-2: A-fragments straight from tls (conflict-free), fragment B
#pragma unroll
    for (int i = 0; i < 4; ++i)
#pragma unroll
        for (int j = 0; j < 4; ++j) acc[i][j] = (f32x4){0.f, 0.f, 0.f, 0.f};
#pragma unroll 2
    for (int ks = 0; ks < KS; ++ks) {
        bf16x8 af[4], bh[4], bl[4];
#pragma unroll
        for (int j = 0; j < 4; ++j) {
            bh[j] = *reinterpret_cast<const bf16x8*>(f2h + (j * KS + ks) * 512);
            bl[j] = *reinterpret_cast<const bf16x8*>(f2l + (j * KS + ks) * 512);
        }
#pragma unroll
        for (int i = 0; i < 4; ++i)
            af[i] = *reinterpret_cast<const bf16x8*>(&tls[((i * 8 + ks) * 64 + lane) * 8]);
#pragma unroll
        for (int i = 0; i < 4; ++i)
#pragma unroll
            for (int j = 0; j < 4; ++j) {
                acc[i][j] = __builtin_amdgcn_mfma_f32_16x16x32_bf16(af[i], bl[j], acc[i][j], 0, 0, 0);
                acc[i][j] = __builtin_amdgcn_mfma_f32_16x16x32_bf16(af[i], bh[j], acc[i][j], 0, 0, 0);
            }
    }
    __syncthreads();   // all tls reads done before overwrite with z

    // epilogue-2: stats (register-only, per-wave direct) + z -> tls slice-major-local
#pragma unroll
    for (int j = 0; j < 4; ++j) {
        int col = wid * 64 + j * 16 + lm;
        float bv = b2[col];
        float s = 0.f, s2 = 0.f;
#pragma unroll
        for (int i = 0; i < 4; ++i) {
#pragma unroll
            for (int r = 0; r < 4; ++r) {
                int row = i * 16 + q * 4 + r;
                float v = acc[i][j][r] + bv;
                if (m0 + row < M) { s += v; s2 = fmaf(v, v, s2); }
                tls[(col >> 5) * 2048 + row * 32 + (col & 31)] = f2bf(v);
            }
        }
        s += __shfl_xor(s, 16); s += __shfl_xor(s, 32);
        s2 += __shfl_xor(s2, 16); s2 += __shfl_xor(s2, 32);
        if (q == 0) {
            statsbuf[(size_t)blockIdx.x * 512 + col] = s;
            statsbuf[(size_t)blockIdx.x * 512 + 256 + col] = s2;
        }
    }
    __syncthreads();
#pragma unroll
    for (int c0 = 0; c0 < 8; ++c0) {
        int o = (c0 * 256 + tid) * 8;
        int sl = o >> 11;
        uint4 v = *reinterpret_cast<const uint4*>(&tls[o]);
        *reinterpret_cast<uint4*>(Z + (size_t)sl * SLS + (size_t)m0 * 32 + (o - (sl << 11))) = v;
    }
}

// ---- stats reduce stage 1: 32 blocks x 512 thr over 782 block-slabs
__global__ __launch_bounds__(512) void k_statred1(const float* __restrict__ statsbuf,
                                                  float* __restrict__ spart) {
    int b = blockIdx.x, t = threadIdx.x;
    int x0 = b * 25, x1 = x0 + 25;
    if (x1 > NMB) x1 = NMB;
    float s = 0.f;
    for (int bx = x0; bx < x1; ++bx)
        s += statsbuf[(size_t)bx * 512 + t];
    spart[b * 512 + t] = s;
}

// ---- stats reduce stage 2: finalize BN affine  A=gamma*inv, B=beta-mean*A
__global__ void k_statred2(const float* __restrict__ spart, const float* __restrict__ gamma,
                           const float* __restrict__ beta, float* __restrict__ Ap,
                           float* __restrict__ Bp) {
    int c = threadIdx.x;   // 256
    float s = 0.f, s2 = 0.f;
#pragma unroll 8
    for (int b = 0; b < 32; ++b) {
        s += spart[b * 512 + c];
        s2 += spart[b * 512 + 256 + c];
    }
    float mean = s * (1.f / N_NODES);
    float var = s2 * (1.f / N_NODES) - mean * mean;
    float inv = rsqrtf(var + 1e-5f);
    float A = gamma[c] * inv;
    Ap[c] = A;
    Bp[c] = beta[c] - mean * A;
}

// ---- vectorized graph mean-pool of relu(A*z+B); writes h back IN PLACE.
// 8 groups of 32 lanes; group = slice; lane = (row-sub 0..7, chan-chunk 0..3).
__global__ void k_pool(unsigned short* __restrict__ z, const float* __restrict__ Ap,
                       const float* __restrict__ Bp, const int* __restrict__ gstart,
                       float* __restrict__ partl) {
    int g = blockIdx.x, sp = blockIdx.y, tid = threadIdx.x;
    int grp = tid >> 5, l = tid & 31;
    int rsub = l >> 2, cc = l & 3;
    float A[8], B[8];
#pragma unroll
    for (int i = 0; i < 8; ++i) {
        A[i] = Ap[grp * 32 + cc * 8 + i];
        B[i] = Bp[grp * 32 + cc * 8 + i];
    }
    int beg = gstart[g], c = gstart[g + 1] - beg;
    int chunk = (c + 3) >> 2;
    int r0 = beg + sp * chunk;
    int r1 = beg + c;
    int rlim = r0 + chunk;
    if (rlim < r1) r1 = rlim;
    unsigned short* zp = z + (size_t)grp * SLS + cc * 8;
    float acc[8] = {0.f, 0.f, 0.f, 0.f, 0.f, 0.f, 0.f, 0.f};
    for (int r = r0 + rsub; r < r1; r += 8) {
        uint4 v = *reinterpret_cast<const uint4*>(zp + (size_t)r * 32);
        const unsigned short* pv = (const unsigned short*)&v;
        uint4 o;
        unsigned short* pw = (unsigned short*)&o;
#pragma unroll
        for (int i = 0; i < 8; ++i) {
            float x = fmaxf(fmaf(A[i], bf2f(pv[i]), B[i]), 0.f);
            pw[i] = f2bf(x);
            acc[i] += x;
        }
        *reinterpret_cast<uint4*>(zp + (size_t)r * 32) = o;
    }
#pragma unroll
    for (int m = 4; m <= 16; m <<= 1)
#pragma unroll
        for (int i = 0; i < 8; ++i) acc[i] += __shfl_xor(acc[i], m, 64);
    if (rsub == 0) {
        float* pp = partl + (size_t)(g * 4 + sp) * 256 + grp * 32 + cc * 8;
#pragma unroll
        for (int i = 0; i < 8; ++i) pp[i] = acc[i];
    }
}

// ---- FC head: sums pool partials, divides by cnt, 2-layer MLP
__global__ __launch_bounds__(1024) void k_fc(const float* __restrict__ part,
                                             const int* __restrict__ gstart,
                                             const float* __restrict__ W1,
                                             const float* __restrict__ b1,
                                             const float* __restrict__ W2,
                                             const float* __restrict__ b2,
                                             float* __restrict__ out) {
    __shared__ float gs[DIM * NLAYERS];
    __shared__ float pt[8][128];
    __shared__ float red2[2];
    int g = blockIdx.x, t = threadIdx.x;
    float invc = 1.f / fmaxf((float)(gstart[g + 1] - gstart[g]), 1.f);
    for (int i = t; i < DIM * NLAYERS; i += 1024) {
        int l = i >> 8, c = i & 255;
        const float* pl = part + ((size_t)(l * NGRAPHS + g) * 4) * 256 + c;
        gs[i] = (pl[0] + pl[256] + pl[512] + pl[768]) * invc;
    }
    __syncthreads();
    int o = t & 127, kk = t >> 7;
    float acc = 0.f;
    const float* wp = W1 + (size_t)(kk * 96) * 128 + o;
#pragma unroll 4
    for (int k = 0; k < 96; ++k) acc = fmaf(gs[kk * 96 + k], wp[(size_t)k * 128], acc);
    pt[kk][o] = acc;
    __syncthreads();
    if (t < 128) {
        float v = b1[o];
#pragma unroll
        for (int p = 0; p < 8; ++p) v += pt[p][o];
        v = fmaxf(v, 0.f) * W2[o];
#pragma unroll
        for (int off = 32; off; off >>= 1) v += __shfl_down(v, off, 64);
        if ((t & 63) == 0) red2[t >> 6] = v;
    }
    __syncthreads();
    if (t == 0) out[g] = red2[0] + red2[1] + b2[0];
}

extern "C" void kernel_launch(void* const* d_in, const int* in_sizes, int n_in,
                              void* d_out, int out_size, void* d_ws, size_t ws_size,
                              hipStream_t stream) {
    const float* x = (const float*)d_in[0];
    const int* ei = (const int*)d_in[1];
    const int* batch = (const int*)d_in[2];
    const float* W_enc = (const float*)d_in[4];
    const float* b_enc = (const float*)d_in[5];
    const float* W1 = (const float*)d_in[6];
    const float* b1 = (const float*)d_in[7];
    const float* W2 = (const float*)d_in[8];
    const float* b2 = (const float*)d_in[9];
    const float* gamma = (const float*)d_in[10];
    const float* beta = (const float*)d_in[11];
    const float* Wfc1 = (const float*)d_in[12];
    const float* bfc1 = (const float*)d_in[13];
    const float* Wfc2 = (const float*)d_in[14];
    const float* bfc2 = (const float*)d_in[15];
    float* out = (float*)d_out;
    const int* srcp = ei;
    const int* dstp = ei + N_EDGES;

    // Workspace bump allocator (~92 MB)
    char* w = (char*)d_ws;
    auto alloc = [&](size_t b) -> char* {
        char* p = w;
        w += (b + 255) & ~(size_t)255;
        return p;
    };
    unsigned short* xb   = (unsigned short*)alloc((size_t)N_PAD * F_INPUT * 2);  // [4][N_PAD][32]
    unsigned short* hbuf = (unsigned short*)alloc(8 * SLS * 2);  // enc out / z / h (in-place)
    unsigned short* zA   = (unsigned short*)alloc(8 * SLS * 2);  // agg out
    unsigned short* wench = (unsigned short*)alloc(F_INPUT * DIM * 2);
    unsigned short* wencl = (unsigned short*)alloc(F_INPUT * DIM * 2);
    unsigned short* w1h = (unsigned short*)alloc((size_t)NLAYERS * DIM * DIM * 2);
    unsigned short* w1l = (unsigned short*)alloc((size_t)NLAYERS * DIM * DIM * 2);
    unsigned short* w2h = (unsigned short*)alloc((size_t)NLAYERS * DIM * DIM * 2);
    unsigned short* w2l = (unsigned short*)alloc((size_t)NLAYERS * DIM * DIM * 2);
    unsigned short* csr16 = (unsigned short*)alloc((size_t)N_EDGES * 2);
    int* row_ptr = (int*)alloc((size_t)(N_NODES + 1) * 4);
    unsigned* slab = (unsigned*)alloc((size_t)NBH * 25000 * 4);
    int* deg = (int*)alloc((size_t)N_NODES * 4);
    int* basep = (int*)alloc((size_t)NBH * N_NODES * 4);
    int* gstart = (int*)alloc((NGRAPHS + 1) * 4);
    int* bsum = (int*)alloc(256 * 4);
    int* boff = (int*)alloc(256 * 4);
    float* statsbuf = (float*)alloc((size_t)NMB * 512 * 4);
    float* spart = (float*)alloc((size_t)32 * 512 * 4);
    float* Abn = (float*)alloc(256 * 4);
    float* Bbn = (float*)alloc(256 * 4);
    float* part = (float*)alloc((size_t)NLAYERS * NGRAPHS * 4 * 256 * 4);

    // prep: weights hi/lo fragment-packed + x->bf16 slice-major (6250 blocks)
    k_prep<<<6250, 256, 0, stream>>>(W_enc, W1, W2, x, wench, wencl, w1h, w1l, w2h, w2l, xb);

    // CSR build (u16 indices), atomic-free
    const int NB = (N_NODES + 255) / 256;  // 196
    k_count<<<NBH, 512, 0, stream>>>(dstp, slab);
    k_degred<<<NB, 256, 0, stream>>>(slab, batch, deg, gstart);
    k_scan1<<<NB, 256, 0, stream>>>(deg, row_ptr + 1, bsum);
    k_scan2<<<1, 256, 0, stream>>>(bsum, boff, NB);
    k_scan3<<<NB, 256, 0, stream>>>(row_ptr, boff);
    k_base<<<NB, 256, 0, stream>>>(slab, row_ptr, basep);
    k_fill2<<<NBH, 512, 0, stream>>>(srcp, dstp, basep, csr16);

    // encoder: h = x @ W_enc + b_enc -> hbuf (slice-major)
    k_enc<<<NMB, 256, 0, stream>>>(xb, wench, wencl, b_enc, hbuf);

    dim3 pgrid(NGRAPHS, 4);
    const int AGRID = 782 * 8;
    for (int l = 0; l < NLAYERS; ++l) {
        k_agg<<<AGRID, 256, 0, stream>>>(hbuf, row_ptr, csr16, zA);
        k_mlp<<<NMB, 256, 0, stream>>>(zA, w1h + l * 65536, w1l + l * 65536, b1 + l * DIM,
                                       w2h + l * 65536, w2l + l * 65536, b2 + l * DIM,
                                       hbuf, statsbuf, N_NODES);
        k_statred1<<<32, 512, 0, stream>>>(statsbuf, spart);
        k_statred2<<<1, 256, 0, stream>>>(spart, gamma + l * DIM, beta + l * DIM, Abn, Bbn);
        k_pool<<<pgrid, 256, 0, stream>>>(hbuf, Abn, Bbn, gstart, part + (size_t)l * NGRAPHS * 4 * 256);
    }
    k_fc<<<NGRAPHS, 1024, 0, stream>>>(part, gstart, Wfc1, bfc1, Wfc2, bfc2, out);
}